// Round 5
// baseline (151.516 us; speedup 1.0000x reference)
//
#include <hip/hip_runtime.h>
#include <hip/hip_fp16.h>

#define B_ 4
#define D_ 4
#define P_ 12000
#define N_ 100
#define C_ 64
#define GH 496
#define GW 432
#define PN (P_*N_)        /* 1,200,000 */
#define HW (GH*GW)        /* 214,272   */
#define WPB 12            /* waves per fused block */
#define PPB (WPB*8)       /* 96 pillars per fused block */
#define GRID_F (B_*(P_/PPB))  /* 500 fused blocks; partials stride */
#define OVFCAP 4096           /* collision-overflow capacity (expected ~1.5k) */
#define OCH 768               /* k_out cells per block; HW == 768*279 */
#define ONCH (HW/OCH)         /* 279 */

typedef float v2f __attribute__((ext_vector_type(2)));

// Packed f32 fma (v_pk_fma_f32 on CDNA); scalar fallback keeps identical numerics.
#if defined(__has_builtin)
#if __has_builtin(__builtin_elementwise_fma)
#define HAVE_EW_FMA 1
#endif
#endif
__device__ __forceinline__ v2f fma2(v2f a, v2f b, v2f c) {
#ifdef HAVE_EW_FMA
    return __builtin_elementwise_fma(a, b, c);
#else
    v2f r; r.x = fmaf(a.x, b.x, c.x); r.y = fmaf(a.y, b.y, c.y); return r;
#endif
}
__device__ __forceinline__ v2f max2(v2f a, v2f b) {
    v2f r; r.x = fmaxf(a.x, b.x); r.y = fmaxf(a.y, b.y); return r;
}

// ---- workspace layout (total 9,617,408 B) ----
static constexpr size_t OFF_PART  = 0;                          // partials [14][GRID_F] f32
static constexpr size_t PART_BYTES= 14*(size_t)GRID_F*4;        // 28,000
static constexpr size_t OFF_CTL   = (OFF_PART + PART_BYTES + 63) & ~(size_t)63;  // ovfcnt
static constexpr size_t OFF_SLOT  = 28672;
static constexpr size_t SLOT_BYTES= (size_t)B_*HW*4;            // 3,428,352
static constexpr size_t OFF_OVF   = OFF_SLOT + SLOT_BYTES;      // 3,457,024
static constexpr size_t OFF_U     = OFF_OVF + (size_t)OVFCAP*4; // 3,473,408 (256-aligned)
static constexpr size_t U_BYTES   = (size_t)B_*P_*C_*2;         // 6,144,000 (fp16)

// VALU-only 8-lane-group max reduction step
template<int CTRL>
__device__ __forceinline__ float dppmax(float v) {
    int s = __builtin_amdgcn_update_dpp(0, __float_as_int(v), CTRL, 0xf, 0xf, true);
    return fmaxf(v, __int_as_float(s));
}

// Shared stats routine: reduce partials [14][GRID_F] in f64 (fixed order ->
// deterministic and identical in every block), then st[c] = {sc, shift} into
// sst[2c], sst[2c+1]. Requires >=224 threads; caller syncs before use.
__device__ __forceinline__ void block_stats(const float* __restrict__ partials,
                                            const float* __restrict__ Wm,
                                            const float* __restrict__ gamma,
                                            const float* __restrict__ beta,
                                            double* smom /*[14]*/,
                                            float*  sst  /*[128]*/) {
    int t = threadIdx.x;
    if (t < 224) {                            // 14 groups x 16 lanes (wave-aligned)
        int j = t >> 4, l = t & 15;
        double s = 0.0;
        for (int i = l; i < GRID_F; i += 16)
            s += (double)partials[(size_t)j*GRID_F + i];
        #pragma unroll
        for (int off = 8; off; off >>= 1) s += __shfl_down(s, off);
        if (l == 0) smom[j] = s;
    }
    __syncthreads();
    if (t < C_) {
        int c = t;
        double S[4];
        #pragma unroll
        for (int d = 0; d < 4; ++d) S[d] = smom[d];
        double M[4][4];
        int k = 4;
        for (int i = 0; i < 4; ++i)
            for (int j = i; j < 4; ++j) { M[i][j] = smom[k]; M[j][i] = smom[k]; ++k; }
        double w[4];
        #pragma unroll
        for (int d = 0; d < 4; ++d) w[d] = (double)Wm[c*4+d];
        const double NT = (double)B_ * (double)PN;
        double mean = 0.0;
        #pragma unroll
        for (int d = 0; d < 4; ++d) mean += w[d]*S[d];
        mean /= NT;
        double ey2 = 0.0;
        for (int i = 0; i < 4; ++i)
            for (int j = 0; j < 4; ++j) ey2 += w[i]*w[j]*M[i][j];
        ey2 /= NT;
        double var = ey2 - mean*mean;
        double inv = 1.0 / sqrt(var + 1e-5);
        double sc  = (double)gamma[c] * inv;
        sst[c*2]     = (float)sc;
        sst[c*2 + 1] = (float)((double)beta[c] - mean*sc);
    }
}

// Slot allocation: DETERMINISTIC winner = max pillar id per cell (atomicMax).
__global__ __launch_bounds__(256) void k_alloc(const int* __restrict__ idx,
                                               int* __restrict__ slot,
                                               int* __restrict__ ovf,
                                               int* __restrict__ ovfcnt) {
    const int BPB = (P_ + 255)/256;           // 47 blocks per batch
    int b = blockIdx.x / BPB;
    int p = (blockIdx.x % BPB)*256 + threadIdx.x;
    if (p >= P_) return;
    size_t bp = (size_t)b*P_ + p;
    int h = idx[bp*2], w = idx[bp*2 + 1];
    int cell = h*GW + w;
    int old = atomicMax(&slot[(size_t)b*HW + cell], p);
    if (old != -1) {                          // collision: smaller of {old,p} loses
        int loser = (old < p) ? old : p;
        int at = atomicAdd(ovfcnt, 1);
        if (at < OVFCAP) ovf[at] = b*P_ + loser;
    }
}

// Fused single x pass: BN moment partials (per-block f32 slot, NO atomics/fences)
// and raw per-pillar conv maxes u[b][p][c] = max_n (W[c,:]·x[:,p,n]), fp16.
// Affine+relu deferred to k_out/k_fixup (sc > 0 so max commutes with affine).
__global__ __launch_bounds__(768) void k_fused(const float* __restrict__ x,
                                               const float* __restrict__ Wm,
                                               float* __restrict__ partials,
                                               __half* __restrict__ uraw) {
    __shared__ float tr[WPB][8*65 + 8];       // per-wave transpose, pad vs banks
    __shared__ float red[WPB][14];
    const int BPB = P_/PPB;                   // 125 blocks per batch
    int b    = blockIdx.x / BPB;
    int pblk = (blockIdx.x % BPB)*PPB;
    int lane = threadIdx.x & 63;
    int wv   = threadIdx.x >> 6;
    int pl   = lane >> 3;
    int oct  = lane & 7;
    int p    = pblk + wv*8 + pl;
    const float* xb = x + (size_t)b*D_*PN + (size_t)p*N_;

    float4 xq[3][4];                          // [j][d]
    #pragma unroll
    for (int j = 0; j < 3; ++j) {
        int n = 4*oct + 32*j;
        #pragma unroll
        for (int d = 0; d < 4; ++d)
            xq[j][d] = *reinterpret_cast<const float4*>(xb + n + (size_t)d*PN);
    }
    float x13[4];                             // tail slot
    #pragma unroll
    for (int d = 0; d < 4; ++d)
        x13[d] = (oct < 4) ? xb[96 + oct + (size_t)d*PN] : xq[0][d].x;

    // ---- moments (packed): s01={s0,s1} s23={s2,s3}, a0={m00,m11} a1={m01,m12}
    // a2={m02,m13} a3={m03,m23} a4={m22,m33}.
    {
        v2f s01 = {0.f,0.f}, s23 = {0.f,0.f};
        v2f a0 = {0.f,0.f}, a1 = {0.f,0.f}, a2 = {0.f,0.f}, a3 = {0.f,0.f}, a4 = {0.f,0.f};
        #pragma unroll
        for (int j = 0; j < 3; ++j) {
            #pragma unroll
            for (int e = 0; e < 4; ++e) {
                float x0 = ((const float*)&xq[j][0])[e];
                float x1 = ((const float*)&xq[j][1])[e];
                float x2 = ((const float*)&xq[j][2])[e];
                float x3 = ((const float*)&xq[j][3])[e];
                v2f q01 = {x0,x1}, q12 = {x1,x2}, q23 = {x2,x3}, q02 = {x0,x2}, q33 = {x3,x3};
                s01 += q01; s23 += q23;
                a0 = fma2(q01, q01, a0);
                a1 = fma2(q01, q12, a1);
                a2 = fma2(q01, q23, a2);
                a3 = fma2(q02, q33, a3);
                a4 = fma2(q23, q23, a4);
            }
        }
        if (oct < 4) {                        // genuine tail n = 96..99
            float x0 = x13[0], x1 = x13[1], x2 = x13[2], x3 = x13[3];
            v2f q01 = {x0,x1}, q12 = {x1,x2}, q23 = {x2,x3}, q02 = {x0,x2}, q33 = {x3,x3};
            s01 += q01; s23 += q23;
            a0 = fma2(q01, q01, a0);
            a1 = fma2(q01, q12, a1);
            a2 = fma2(q01, q23, a2);
            a3 = fma2(q02, q33, a3);
            a4 = fma2(q23, q23, a4);
        }
        float v[14] = {s01.x, s01.y, s23.x, s23.y,
                       a0.x, a1.x, a2.x, a3.x,      /* m00 m01 m02 m03 */
                       a0.y, a1.y, a2.y,            /* m11 m12 m13 */
                       a4.x, a3.y, a4.y};           /* m22 m23 m33 */
        #pragma unroll
        for (int j = 0; j < 14; ++j) {
            float t = v[j];
            #pragma unroll
            for (int off = 32; off; off >>= 1) t += __shfl_down(t, off);
            if (lane == 0) red[wv][j] = t;
        }
        __syncthreads();
        if (threadIdx.x < 14) {
            int j = threadIdx.x;
            float t = 0.f;
            #pragma unroll
            for (int w2 = 0; w2 < WPB; ++w2) t += red[w2][j];
            partials[(size_t)j*GRID_F + blockIdx.x] = t;    // per-block slot, no atomics
        }
    }

    // ---- conv-max, channel-pair packed ----
    for (int c = 0; c < C_; c += 2) {
        const float4 wA = *reinterpret_cast<const float4*>(Wm + c*4);
        const float4 wB = *reinterpret_cast<const float4*>(Wm + (c+1)*4);
        v2f wp0 = {wA.x, wB.x}, wp1 = {wA.y, wB.y};
        v2f wp2 = {wA.z, wB.z}, wp3 = {wA.w, wB.w};
        v2f m = {-3.4e38f, -3.4e38f};
        #pragma unroll
        for (int j = 0; j < 3; ++j) {
            #pragma unroll
            for (int e = 0; e < 4; ++e) {
                float v0 = ((const float*)&xq[j][0])[e];
                float v1 = ((const float*)&xq[j][1])[e];
                float v2 = ((const float*)&xq[j][2])[e];
                float v3 = ((const float*)&xq[j][3])[e];
                v2f dot = wp3 * v3;
                dot = fma2(wp2, v2f{v2, v2}, dot);
                dot = fma2(wp1, v2f{v1, v1}, dot);
                dot = fma2(wp0, v2f{v0, v0}, dot);
                m = max2(m, dot);
            }
        }
        {
            v2f dot = wp3 * x13[3];
            dot = fma2(wp2, v2f{x13[2], x13[2]}, dot);
            dot = fma2(wp1, v2f{x13[1], x13[1]}, dot);
            dot = fma2(wp0, v2f{x13[0], x13[0]}, dot);
            m = max2(m, dot);
        }
        float mA = m.x, mB = m.y;
        mA = dppmax<0xB1>(mA); mA = dppmax<0x4E>(mA); mA = dppmax<0x141>(mA);
        mB = dppmax<0xB1>(mB); mB = dppmax<0x4E>(mB); mB = dppmax<0x141>(mB);
        if (oct == (c >> 3)) {                // c even: both c, c+1 same octant
            tr[wv][pl*65 + c]     = mA;
            tr[wv][pl*65 + c + 1] = mB;
        }
    }
    __builtin_amdgcn_s_waitcnt(0);            // drain LDS writes (wave-local use)
    // coalesced 128B half rows (no atomics)
    for (int pi = 0; pi < 8; ++pi)
        uraw[((size_t)b*P_ + pblk + wv*8 + pi)*C_ + lane] =
            __float2half(tr[wv][pi*65 + lane]);
}

// Output streamer: block = (b, 768-cell chunk). slot chunk read ONCE into LDS.
// Stats computed per-block from partials (deterministic, ~1 us, hidden under
// block concurrency) -- no separate k_stats dispatch. 8 channel-groups:
// winner rows (fp16, 128 B, sparse ~6%) gathered as one 16 B load per cell per
// group; LDS tile c-major [8][OCH] stride-1 conflict-free both phases.
__global__ __launch_bounds__(256) void k_out(const int* __restrict__ slot,
                                             const __half* __restrict__ uraw,
                                             const float* __restrict__ partials,
                                             const float* __restrict__ Wm,
                                             const float* __restrict__ gamma,
                                             const float* __restrict__ beta,
                                             float* __restrict__ out) {
    __shared__ float tile[8][OCH];
    __shared__ int   sslot[OCH];
    __shared__ double smom[14];
    __shared__ float  sst[128];
    int b     = blockIdx.x / ONCH;
    int chunk = blockIdx.x % ONCH;
    int cell0 = chunk*OCH;
    int t = threadIdx.x;
    block_stats(partials, Wm, gamma, beta, smom, sst);   // includes one syncthreads
    #pragma unroll
    for (int k = 0; k < OCH/256; ++k)
        sslot[k*256 + t] = slot[(size_t)b*HW + cell0 + k*256 + t];
    __syncthreads();                                     // sst + sslot ready
    const __half* vb = uraw + (size_t)b*P_*C_;
    for (int g = 0; g < 8; ++g) {
        #pragma unroll
        for (int k = 0; k < OCH/256; ++k) {
            int cell = k*256 + t;
            int s = sslot[cell];
            if (s >= 0) {
                float4 raw = *reinterpret_cast<const float4*>(vb + (size_t)s*C_ + g*8);
                const __half2* h2 = reinterpret_cast<const __half2*>(&raw);
                tile[0][cell] = __low2float(h2[0]); tile[1][cell] = __high2float(h2[0]);
                tile[2][cell] = __low2float(h2[1]); tile[3][cell] = __high2float(h2[1]);
                tile[4][cell] = __low2float(h2[2]); tile[5][cell] = __high2float(h2[2]);
                tile[6][cell] = __low2float(h2[3]); tile[7][cell] = __high2float(h2[3]);
            } else {
                #pragma unroll
                for (int q = 0; q < 8; ++q) tile[q][cell] = 0.f;
            }
        }
        __syncthreads();
        #pragma unroll
        for (int cp = 0; cp < 8; ++cp) {
            int c = g*8 + cp;
            float scc = sst[c*2], shc = sst[c*2+1];
            float* ob = out + ((size_t)b*C_ + c)*HW + cell0;
            #pragma unroll
            for (int k = 0; k < OCH/256; ++k) {
                int cell = k*256 + t;
                float y = 0.f;
                if (sslot[cell] >= 0)
                    y = fmaxf(fmaf(scc, tile[cp][cell], shc), 0.f);
                ob[cell] = y;
            }
        }
        __syncthreads();
    }
}

// Add collision losers' affine+relu'd rows directly into out (after k_out).
// Computes st per-block via the same deterministic routine.
__global__ __launch_bounds__(256) void k_fixup(const int* __restrict__ ovf,
                                               const int* __restrict__ ovfcnt,
                                               const int* __restrict__ idx,
                                               const __half* __restrict__ uraw,
                                               const float* __restrict__ partials,
                                               const float* __restrict__ Wm,
                                               const float* __restrict__ gamma,
                                               const float* __restrict__ beta,
                                               float* __restrict__ out) {
    __shared__ double smom[14];
    __shared__ float  sst[128];
    block_stats(partials, Wm, gamma, beta, smom, sst);
    __syncthreads();
    int n = *ovfcnt;
    if (n > OVFCAP) n = OVFCAP;
    int lane = threadIdx.x & 63;
    int wid  = (blockIdx.x*256 + threadIdx.x) >> 6;
    int nw   = gridDim.x*4;
    float scc = sst[lane*2], shc = sst[lane*2+1];
    for (int e = wid; e < n; e += nw) {
        int bp = ovf[e];
        int b  = bp / P_;
        int h = idx[(size_t)bp*2], w = idx[(size_t)bp*2 + 1];
        int cell = h*GW + w;
        float u = __half2float(uraw[(size_t)bp*C_ + lane]);
        float y = fmaxf(fmaf(scc, u, shc), 0.0f);
        if (y > 0.0f)
            atomicAdd(&out[((size_t)b*C_ + lane)*HW + cell], y);
    }
}

extern "C" void kernel_launch(void* const* d_in, const int* in_sizes, int n_in,
                              void* d_out, int out_size, void* d_ws, size_t ws_size,
                              hipStream_t stream) {
    const float* x     = (const float*)d_in[0];
    const int*   idx   = (const int*)  d_in[1];
    const float* Wm    = (const float*)d_in[2];
    const float* gamma = (const float*)d_in[3];
    const float* beta  = (const float*)d_in[4];
    float* out = (float*)d_out;

    char* ws = (char*)d_ws;
    float*  partials = (float*) (ws + OFF_PART);
    int*    ovfcnt   = (int*)   (ws + OFF_CTL);
    int*    slot     = (int*)   (ws + OFF_SLOT);
    int*    ovf      = (int*)   (ws + OFF_OVF);
    __half* uraw     = (__half*)(ws + OFF_U);

    hipMemsetAsync(ws + OFF_SLOT, 0xFF, SLOT_BYTES, stream);   // slot <- -1
    hipMemsetAsync(ws + OFF_CTL, 0, 64, stream);               // ovfcnt <- 0
    k_alloc<<<B_*((P_ + 255)/256), 256, 0, stream>>>(idx, slot, ovf, ovfcnt);
    k_fused<<<GRID_F, WPB*64, 0, stream>>>(x, Wm, partials, uraw);
    k_out  <<<B_*ONCH, 256, 0, stream>>>(slot, uraw, partials, Wm, gamma, beta, out);
    k_fixup<<<32, 256, 0, stream>>>(ovf, ovfcnt, idx, uraw, partials, Wm, gamma, beta, out);
}